// Round 13
// baseline (178.213 us; speedup 1.0000x reference)
//
#include <hip/hip_runtime.h>
#include <hip/hip_bf16.h>

#define BB 4
#define CC 64
#define HH 128
#define WW 128
#define HW (HH * WW)
#define OCP 20  // offset channels, padded (18 used)

typedef short bf16x8 __attribute__((ext_vector_type(8)));
typedef float f32x4 __attribute__((ext_vector_type(4)));
typedef float f32x2 __attribute__((ext_vector_type(2)));

static __device__ __forceinline__ short f2bf(float f) {
  __hip_bfloat16 h = __float2bfloat16(f);
  return __builtin_bit_cast(short, h);
}
static __device__ __forceinline__ float bf2f(short s) {
  unsigned int u = ((unsigned int)(unsigned short)s) << 16;
  return __builtin_bit_cast(float, u);
}

// async 16B/lane global -> LDS (wave-uniform LDS base + lane*16)
static __device__ __forceinline__ void stage1k(const short* g, short* lds) {
  __builtin_amdgcn_global_load_lds(
      (const __attribute__((address_space(1))) unsigned int*)g,
      (__attribute__((address_space(3))) unsigned int*)lds, 16, 0, 0);
}

// NCHW f32 -> NHWC bf16 for two tensors. Block = 64 px x 64 c tile.
__global__ __launch_bounds__(256) void cast_nhwc_kernel(
    const float* __restrict__ a, const float* __restrict__ b,
    short* __restrict__ oa, short* __restrict__ ob) {
  __shared__ float tile[64][68];
  const int bid = blockIdx.x;        // 1024 blocks
  const int bb = bid >> 8;           // batch
  const int hw0 = (bid & 255) * 64;  // 64-px stripe
  const int t = threadIdx.x;
  for (int s = 0; s < 2; s++) {
    const float* src = s ? b : a;
    short* dst = s ? ob : oa;
    if (s) __syncthreads();
    {
      const int lp = t & 15;  // 16 lanes x float4 = 64 px
      for (int c = (t >> 4); c < 64; c += 16) {
        float4 v = *(const float4*)&src[((size_t)(bb * 64 + c)) * HW + hw0 + lp * 4];
        *(float4*)&tile[c][lp * 4] = v;
      }
    }
    __syncthreads();
    {
      const int px = t >> 2;
      const int seg = t & 3;
      bf16x8 s0, s1;
#pragma unroll
      for (int i = 0; i < 8; i++) s0[i] = f2bf(tile[seg * 16 + i][px]);
#pragma unroll
      for (int i = 0; i < 8; i++) s1[i] = f2bf(tile[seg * 16 + 8 + i][px]);
      short* dp = dst + ((size_t)(bid * 64 + px)) * 64 + seg * 16;
      *(bf16x8*)dp = s0;
      *(bf16x8*)(dp + 8) = s1;
    }
  }
}

// Weight prep, all 3 stages in one launch (stage = blockIdx.x/144).
__global__ __launch_bounds__(256) void prep_weights_all(
    const float* __restrict__ wd1, const float* __restrict__ wo1,
    short* __restrict__ wtd1, short* __restrict__ wtoff1,
    const float* __restrict__ wd2, const float* __restrict__ wo2,
    short* __restrict__ wtd2, short* __restrict__ wtoff2,
    const float* __restrict__ wd3, const float* __restrict__ wo3,
    short* __restrict__ wtd3, short* __restrict__ wtoff3) {
  const int s = blockIdx.x / 144;
  const float* wd = (s == 0) ? wd1 : (s == 1) ? wd2 : wd3;
  const float* wo = (s == 0) ? wo1 : (s == 1) ? wo2 : wo3;
  short* wtd = (s == 0) ? wtd1 : (s == 1) ? wtd2 : wtd3;
  short* wtoff = (s == 0) ? wtoff1 : (s == 1) ? wtoff2 : wtoff3;
  const int i = (blockIdx.x % 144) * 256 + threadIdx.x;  // 0..36863
  const int j = i & 7, l = (i >> 3) & 63, f = i >> 9;
  {
    int ot = f & 3, cf = (f >> 2) & 1, k = f >> 3;
    int o = ot * 16 + (l & 15), c = cf * 32 + (l >> 4) * 8 + j;
    wtd[i] = f2bf(wd[(o * 64 + c) * 9 + k]);
  }
  {
    int ot = f & 1, ks = f >> 1;
    int cs = ks & 3, k = ks >> 2;
    int o = ot * 16 + (l & 15), c = cs * 32 + (l >> 4) * 8 + j;
    wtoff[i] = (o < 18) ? f2bf(wo[(o * 128 + c) * 9 + k]) : (short)0;
  }
}

// ---------- MFMA offset conv, split-K(cs) across 4 waves (r8) ----------
__global__ __launch_bounds__(256, 8) void off_conv_kernel(
    const short* __restrict__ ref, const short* __restrict__ x2,
    const short* __restrict__ wtoff, const float* __restrict__ bias,
    float* __restrict__ out) {
  __shared__ float red[2][64][9];
  int bid = blockIdx.x;
  bid = (bid & 7) * (gridDim.x >> 3) + (bid >> 3);
  const int tid = threadIdx.x;
  const int l = tid & 63;
  const int cs = __builtin_amdgcn_readfirstlane(tid >> 6);
  const int col = l & 15, quad = l >> 4;
  const int pix = bid * 16 + col;
  const int b = pix >> 14, hw = pix & (HW - 1);
  const int h = hw >> 7, w = hw & (WW - 1);

  f32x4 acc0 = {0.f, 0.f, 0.f, 0.f}, acc1 = {0.f, 0.f, 0.f, 0.f};
  const int c0 = (cs & 1) * 32 + quad * 8;
  const short* src = (cs < 2) ? ref : x2;
  const bf16x8* wp = (const bf16x8*)wtoff + l;

#pragma unroll
  for (int k = 0; k < 9; k++) {
    const int ky = k / 3, kx = k - ky * 3;
    const int hh = h + ky - 1, ww2 = w + kx - 1;
    const bool valid = (hh >= 0) & (hh < HH) & (ww2 >= 0) & (ww2 < WW);
    const int chh = min(max(hh, 0), HH - 1), cww = min(max(ww2, 0), WW - 1);
    bf16x8 v = *(const bf16x8*)(src + ((b * HW + chh * WW + cww) << 6) + c0);
    if (!valid) v = (bf16x8)(short)0;
    acc0 = __builtin_amdgcn_mfma_f32_16x16x32_bf16(
        wp[((k * 4 + cs) * 2 + 0) * 64], v, acc0, 0, 0, 0);
    acc1 = __builtin_amdgcn_mfma_f32_16x16x32_bf16(
        wp[((k * 4 + cs) * 2 + 1) * 64], v, acc1, 0, 0, 0);
  }

  if (cs >= 2) {
#pragma unroll
    for (int r = 0; r < 4; r++) {
      red[cs - 2][l][r] = acc0[r];
      red[cs - 2][l][4 + r] = acc1[r];
    }
  }
  __syncthreads();
  if (cs < 2) {
#pragma unroll
    for (int r = 0; r < 4; r++) {
      acc0[r] += red[cs][l][r];
      acc1[r] += red[cs][l][4 + r];
    }
  }
  __syncthreads();
  if (cs == 1) {
#pragma unroll
    for (int r = 0; r < 4; r++) {
      red[0][l][r] = acc0[r];
      red[0][l][4 + r] = acc1[r];
    }
  }
  __syncthreads();
  if (cs == 0) {
    float* po = out + (size_t)pix * OCP;
#pragma unroll
    for (int r = 0; r < 4; r++)
      po[quad * 4 + r] = acc0[r] + red[0][l][r] + bias[quad * 4 + r];
    if (quad == 0) {
      po[16] = acc1[0] + red[0][l][4] + bias[16];
      po[17] = acc1[1] + red[0][l][5] + bias[17];
    }
  }
}

// ---------- LDS-tiled MFMA deformable conv, cf-split ----------
// Block = 512 thr = 8 waves = 4 row-groups x 2 channel-halves.
// Output tile = 4 rows x 16 cols px; halo tile 12x24 px (36.9KB, chunk-
// swizzled). Per wave per tap: 4 ds_read_b128 + half blend + 4 MFMA.
// Reduction reuses the tile buffer (dead after the k-loop).
#define TH 12
#define TWP 24
__global__ __launch_bounds__(512, 6) void deform_cft_kernel(
    const short* __restrict__ x, const float* __restrict__ off,
    const short* __restrict__ wtd, const float* __restrict__ bias,
    float* __restrict__ outf, short* __restrict__ outb) {
  __shared__ short tile[TH * TWP * 64];  // 36,864 B
  int bid = blockIdx.x;
  bid = (bid & 7) * (gridDim.x >> 3) + (bid >> 3);  // 1024 % 8 == 0
  const int tid = threadIdx.x;
  const int l = tid & 63;
  const int wv = __builtin_amdgcn_readfirstlane(tid >> 6);  // 0..7
  const int g = wv >> 1;   // row-group 0..3
  const int cf = wv & 1;   // channel half
  const int col = l & 15, quad = l >> 4;
  const int b = bid >> 8;          // 256 blocks per batch
  const int rem = bid & 255;
  const int h0 = (rem >> 3) * 4;   // 32 row-tiles
  const int w0 = (rem & 7) * 16;   // 8 col-tiles
  const int oy = h0 - 4, ox = w0 - 4;
  const int h = h0 + g, w = w0 + col;
  const int pix = ((b << 7) + h) * WW + w;

  const short* xb = x + (size_t)b * (HW * 64);

  // ---- stage 12x24-px halo tile, chunk-swizzled source ----
  // 36 wave-loads (12 rows x 3 col-segs); wave stages 8 px (1KB) per load:
  // lane = px_in_seg*8 + dest-slot m; source chunk sc = (m - tcol) & 7.
  {
    const int tc = l >> 3;  // pixel-in-segment 0..7
    const int m = l & 7;    // dest chunk slot
#pragma unroll
    for (int i = 0; i < 5; i++) {
      const int idx = wv + i * 8;  // 0..39, wave-uniform
      if (idx < 36) {
        const int r = idx / 3, seg = idx % 3;
        const int iy = min(max(oy + r, 0), HH - 1);
        const int tcol = seg * 8 + tc;
        const int ix = min(max(ox + tcol, 0), WW - 1);
        const int sc = (m - tcol) & 7;
        stage1k(xb + (((iy << 7) + ix) << 6) + sc * 8,
                &tile[(r * TWP + seg * 8) << 6]);
      }
    }
  }

  // offsets for this wave's 16 pixels
  const float* offp = off + (size_t)pix * OCP;
  f32x4 ov0 = *(const f32x4*)(offp);
  f32x4 ov1 = *(const f32x4*)(offp + 4);
  f32x4 ov2 = *(const f32x4*)(offp + 8);
  f32x4 ov3 = *(const f32x4*)(offp + 12);
  f32x2 ov4 = *(const f32x2*)(offp + 16);
  float offv[18];
#pragma unroll
  for (int i = 0; i < 4; i++) offv[i] = ov0[i];
#pragma unroll
  for (int i = 0; i < 4; i++) offv[4 + i] = ov1[i];
#pragma unroll
  for (int i = 0; i < 4; i++) offv[8 + i] = ov2[i];
#pragma unroll
  for (int i = 0; i < 4; i++) offv[12 + i] = ov3[i];
  offv[16] = ov4[0];
  offv[17] = ov4[1];

  f32x4 acc[4];
#pragma unroll
  for (int ot = 0; ot < 4; ot++)
#pragma unroll
    for (int r = 0; r < 4; r++) acc[ot][r] = 0.f;

  const int ch = cf * 4 + quad;        // this wave's 16B chunk index
  const int c0g = ch * 8;              // global-path channel base
  const bf16x8* wp = (const bf16x8*)wtd + l;

  __syncthreads();  // tile staged (drains vmcnt before barrier)

#pragma unroll
  for (int k = 0; k < 9; k++) {
    const int ky = k / 3, kx = k - ky * 3;
    const float py = (float)(h - 1 + ky) + offv[2 * k];
    const float pxx = (float)(w - 1 + kx) + offv[2 * k + 1];
    const float y0f = floorf(py), x0f = floorf(pxx);
    const float ly = py - y0f, lx = pxx - x0f;
    const int y0 = (int)y0f, x0 = (int)x0f;
    const int y1 = y0 + 1, x1 = x0 + 1;
    float w00 = (1.f - ly) * (1.f - lx), w01 = (1.f - ly) * lx;
    float w10 = ly * (1.f - lx), w11 = ly * lx;
    if (y0 < 0 || y0 >= HH) { w00 = 0.f; w01 = 0.f; }
    if (y1 < 0 || y1 >= HH) { w10 = 0.f; w11 = 0.f; }
    if (x0 < 0 || x0 >= WW) { w00 = 0.f; w10 = 0.f; }
    if (x1 < 0 || x1 >= WW) { w01 = 0.f; w11 = 0.f; }
    const int cy0 = min(max(y0, 0), HH - 1), cy1 = min(max(y1, 0), HH - 1);
    const int cx0 = min(max(x0, 0), WW - 1), cx1 = min(max(x1, 0), WW - 1);

    const int ty0 = cy0 - oy, ty1 = cy1 - oy;
    const int tx0 = cx0 - ox, tx1 = cx1 - ox;
    const bool intile = (ty0 >= 0) & (ty1 < TH) & (tx0 >= 0) & (tx1 < TWP);

    bf16x8 v00, v01, v10, v11;
    if (__builtin_amdgcn_ballot_w64(intile) == ~0ull) {
      // LDS fast path (chunk-swizzled ds_read_b128)
      v00 = *(const bf16x8*)&tile[((ty0 * TWP + tx0) << 6) + (((ch + tx0) & 7) << 3)];
      v01 = *(const bf16x8*)&tile[((ty0 * TWP + tx1) << 6) + (((ch + tx1) & 7) << 3)];
      v10 = *(const bf16x8*)&tile[((ty1 * TWP + tx0) << 6) + (((ch + tx0) & 7) << 3)];
      v11 = *(const bf16x8*)&tile[((ty1 * TWP + tx1) << 6) + (((ch + tx1) & 7) << 3)];
    } else {
      // global fallback (rare: |offset| beyond halo)
      v00 = *(const bf16x8*)(xb + ((cy0 * WW + cx0) << 6) + c0g);
      v01 = *(const bf16x8*)(xb + ((cy0 * WW + cx1) << 6) + c0g);
      v10 = *(const bf16x8*)(xb + ((cy1 * WW + cx0) << 6) + c0g);
      v11 = *(const bf16x8*)(xb + ((cy1 * WW + cx1) << 6) + c0g);
    }

    bf16x8 bs;
#pragma unroll
    for (int j = 0; j < 8; j++) {
      float s = bf2f(v00[j]) * w00 + bf2f(v01[j]) * w01 +
                bf2f(v10[j]) * w10 + bf2f(v11[j]) * w11;
      bs[j] = f2bf(s);
    }

    acc[0] = __builtin_amdgcn_mfma_f32_16x16x32_bf16(
        wp[(k * 8 + cf * 4 + 0) * 64], bs, acc[0], 0, 0, 0);
    acc[1] = __builtin_amdgcn_mfma_f32_16x16x32_bf16(
        wp[(k * 8 + cf * 4 + 1) * 64], bs, acc[1], 0, 0, 0);
    acc[2] = __builtin_amdgcn_mfma_f32_16x16x32_bf16(
        wp[(k * 8 + cf * 4 + 2) * 64], bs, acc[2], 0, 0, 0);
    acc[3] = __builtin_amdgcn_mfma_f32_16x16x32_bf16(
        wp[(k * 8 + cf * 4 + 3) * 64], bs, acc[3], 0, 0, 0);
  }

  // ---- 2-way reduce, reusing the (now dead) tile buffer ----
  float* redf = (float*)tile;  // [4 groups][64 lanes][17 pad] = 17,408 B
  __syncthreads();             // everyone done reading tile
  if (cf == 1) {
#pragma unroll
    for (int ot = 0; ot < 4; ot++)
#pragma unroll
      for (int r = 0; r < 4; r++)
        redf[(g * 64 + l) * 17 + ot * 4 + r] = acc[ot][r];
  }
  __syncthreads();
  if (cf == 0) {
#pragma unroll
    for (int ot = 0; ot < 4; ot++)
#pragma unroll
      for (int r = 0; r < 4; r++)
        acc[ot][r] += redf[(g * 64 + l) * 17 + ot * 4 + r]
                      + bias[ot * 16 + quad * 4 + r];
    if (outb) {
#pragma unroll
      for (int ot = 0; ot < 4; ot++) {
        short4 sv;
        sv.x = f2bf(acc[ot][0]); sv.y = f2bf(acc[ot][1]);
        sv.z = f2bf(acc[ot][2]); sv.w = f2bf(acc[ot][3]);
        *(short4*)(outb + (size_t)pix * 64 + ot * 16 + quad * 4) = sv;
      }
    }
    if (outf) {
      const int hw = pix & (HW - 1);
#pragma unroll
      for (int ot = 0; ot < 4; ot++)
#pragma unroll
        for (int r = 0; r < 4; r++) {
          const int o = ot * 16 + quad * 4 + r;
          outf[(size_t)b * (CC * HW) + (size_t)o * HW + hw] = acc[ot][r];
        }
    }
  }
}

extern "C" void kernel_launch(void* const* d_in, const int* in_sizes, int n_in,
                              void* d_out, int out_size, void* d_ws, size_t ws_size,
                              hipStream_t stream) {
  const float* ref    = (const float*)d_in[0];
  const float* nbr    = (const float*)d_in[1];
  const float* w_off1 = (const float*)d_in[2];
  const float* b_off1 = (const float*)d_in[3];
  const float* w_d1   = (const float*)d_in[4];
  const float* b_d1   = (const float*)d_in[5];
  const float* w_off2 = (const float*)d_in[6];
  const float* b_off2 = (const float*)d_in[7];
  const float* w_d2   = (const float*)d_in[8];
  const float* b_d2   = (const float*)d_in[9];
  const float* w_off3 = (const float*)d_in[10];
  const float* b_off3 = (const float*)d_in[11];
  const float* w_d3   = (const float*)d_in[12];
  const float* b_d3   = (const float*)d_in[13];

  float* out = (float*)d_out;
  char* ws = (char*)d_ws;
  float* off_buf = (float*)(ws);               // 5,242,880 B
  short* ref_bf  = (short*)(ws + 5242880);     // 8,388,608 B each
  short* nbr_bf  = (short*)(ws + 13631488);
  short* d1_bf   = (short*)(ws + 22020096);
  short* d2_bf   = (short*)(ws + 30408704);
  short* wtd1    = (short*)(ws + 38797312);    // 73,728 B each
  short* wtd2    = (short*)(ws + 38871040);
  short* wtd3    = (short*)(ws + 38944768);
  short* wtoff1  = (short*)(ws + 39018496);
  short* wtoff2  = (short*)(ws + 39092224);
  short* wtoff3  = (short*)(ws + 39165952);

  cast_nhwc_kernel<<<1024, 256, 0, stream>>>(ref, nbr, ref_bf, nbr_bf);
  prep_weights_all<<<432, 256, 0, stream>>>(
      w_d1, w_off1, wtd1, wtoff1,
      w_d2, w_off2, wtd2, wtoff2,
      w_d3, w_off3, wtd3, wtoff3);

  const int nblk_oc = BB * HW / 16;  // 4096
  const int nblk_df = BB * HW / 64;  // 1024 tiles of 4x16 px

  off_conv_kernel<<<nblk_oc, 256, 0, stream>>>(ref_bf, nbr_bf, wtoff1, b_off1, off_buf);
  deform_cft_kernel<<<nblk_df, 512, 0, stream>>>(nbr_bf, off_buf, wtd1, b_d1, nullptr, d1_bf);
  off_conv_kernel<<<nblk_oc, 256, 0, stream>>>(ref_bf, d1_bf, wtoff2, b_off2, off_buf);
  deform_cft_kernel<<<nblk_df, 512, 0, stream>>>(d1_bf, off_buf, wtd2, b_d2, nullptr, d2_bf);
  off_conv_kernel<<<nblk_oc, 256, 0, stream>>>(ref_bf, d2_bf, wtoff3, b_off3, off_buf);
  deform_cft_kernel<<<nblk_df, 512, 0, stream>>>(d2_bf, off_buf, wtd3, b_d3, out, nullptr);
}

// Round 14
// 120.766 us; speedup vs baseline: 1.4757x; 1.4757x over previous
//
#include <hip/hip_runtime.h>
#include <hip/hip_bf16.h>

#define BB 4
#define CC 64
#define HH 128
#define WW 128
#define HW (HH * WW)
#define TOTPIX (BB * HW)  // 65536

typedef short bf16x8 __attribute__((ext_vector_type(8)));
typedef float f32x4 __attribute__((ext_vector_type(4)));

static __device__ __forceinline__ short f2bf(float f) {
  __hip_bfloat16 h = __float2bfloat16(f);
  return __builtin_bit_cast(short, h);
}
static __device__ __forceinline__ float bf2f(short s) {
  unsigned int u = ((unsigned int)(unsigned short)s) << 16;
  return __builtin_bit_cast(float, u);
}

// async 16B/lane global -> LDS (wave-uniform LDS base + lane*16)
static __device__ __forceinline__ void stage1k(const short* g, short* lds) {
  __builtin_amdgcn_global_load_lds(
      (const __attribute__((address_space(1))) unsigned int*)g,
      (__attribute__((address_space(3))) unsigned int*)lds, 16, 0, 0);
}

// NCHW f32 -> NHWC bf16 for two tensors. Block = 64 px x 64 c tile.
__global__ __launch_bounds__(256) void cast_nhwc_kernel(
    const float* __restrict__ a, const float* __restrict__ b,
    short* __restrict__ oa, short* __restrict__ ob) {
  __shared__ float tile[64][68];
  const int bid = blockIdx.x;        // 1024 blocks
  const int bb = bid >> 8;           // batch
  const int hw0 = (bid & 255) * 64;  // 64-px stripe
  const int t = threadIdx.x;
  for (int s = 0; s < 2; s++) {
    const float* src = s ? b : a;
    short* dst = s ? ob : oa;
    if (s) __syncthreads();
    {
      const int lp = t & 15;  // 16 lanes x float4 = 64 px
      for (int c = (t >> 4); c < 64; c += 16) {
        float4 v = *(const float4*)&src[((size_t)(bb * 64 + c)) * HW + hw0 + lp * 4];
        *(float4*)&tile[c][lp * 4] = v;
      }
    }
    __syncthreads();
    {
      const int px = t >> 2;
      const int seg = t & 3;
      bf16x8 s0, s1;
#pragma unroll
      for (int i = 0; i < 8; i++) s0[i] = f2bf(tile[seg * 16 + i][px]);
#pragma unroll
      for (int i = 0; i < 8; i++) s1[i] = f2bf(tile[seg * 16 + 8 + i][px]);
      short* dp = dst + ((size_t)(bid * 64 + px)) * 64 + seg * 16;
      *(bf16x8*)dp = s0;
      *(bf16x8*)(dp + 8) = s1;
    }
  }
}

// Weight prep, all 3 stages in one launch (stage = blockIdx.x/144).
__global__ __launch_bounds__(256) void prep_weights_all(
    const float* __restrict__ wd1, const float* __restrict__ wo1,
    short* __restrict__ wtd1, short* __restrict__ wtoff1,
    const float* __restrict__ wd2, const float* __restrict__ wo2,
    short* __restrict__ wtd2, short* __restrict__ wtoff2,
    const float* __restrict__ wd3, const float* __restrict__ wo3,
    short* __restrict__ wtd3, short* __restrict__ wtoff3) {
  const int s = blockIdx.x / 144;
  const float* wd = (s == 0) ? wd1 : (s == 1) ? wd2 : wd3;
  const float* wo = (s == 0) ? wo1 : (s == 1) ? wo2 : wo3;
  short* wtd = (s == 0) ? wtd1 : (s == 1) ? wtd2 : wtd3;
  short* wtoff = (s == 0) ? wtoff1 : (s == 1) ? wtoff2 : wtoff3;
  const int i = (blockIdx.x % 144) * 256 + threadIdx.x;  // 0..36863
  const int j = i & 7, l = (i >> 3) & 63, f = i >> 9;
  {
    int ot = f & 3, cf = (f >> 2) & 1, k = f >> 3;
    int o = ot * 16 + (l & 15), c = cf * 32 + (l >> 4) * 8 + j;
    wtd[i] = f2bf(wd[(o * 64 + c) * 9 + k]);
  }
  {
    int ot = f & 1, ks = f >> 1;
    int cs = ks & 3, k = ks >> 2;
    int o = ot * 16 + (l & 15), c = cs * 32 + (l >> 4) * 8 + j;
    wtoff[i] = (o < 18) ? f2bf(wo[(o * 128 + c) * 9 + k]) : (short)0;
  }
}

// ---------- LDS-tiled MFMA offset conv ----------
// Block = 256 thr = 4 row-waves; output 4x16 px, halo 6x24 px of BOTH
// tensors (36,864 B, chunk-swizzled). Full K=128 per wave: per tap
// 4 ds_read_b128 + 8 MFMA. No reduce. Planar f32 output off[18][TOTPIX].
__global__ __launch_bounds__(256, 4) void off_tile_kernel(
    const short* __restrict__ ref, const short* __restrict__ x2,
    const short* __restrict__ wtoff, const float* __restrict__ bias,
    float* __restrict__ out) {
  __shared__ short tile[2 * 6 * 24 * 64];  // [tensor][row][px][64ch]
  int bid = blockIdx.x;
  bid = (bid & 7) * (gridDim.x >> 3) + (bid >> 3);  // 1024 % 8 == 0
  const int tid = threadIdx.x;
  const int l = tid & 63;
  const int g = __builtin_amdgcn_readfirstlane(tid >> 6);  // row-group 0..3
  const int col = l & 15, quad = l >> 4;
  const int b = bid >> 8;
  const int rem = bid & 255;
  const int h0 = (rem >> 3) * 4;   // 32 row-tiles
  const int w0 = (rem & 7) * 16;   // 8 col-tiles
  const int oy = h0 - 1, ox = w0 - 1;
  const int h = h0 + g, w = w0 + col;
  const int pix = ((b << 7) + h) * WW + w;

  const short* srcs[2] = {ref + (size_t)b * (HW * 64), x2 + (size_t)b * (HW * 64)};

  // ---- stage 2 x 6 rows x 24 px, chunk-swizzled (slot = (chunk+tcol)&7) ----
  {
    const int tc = l >> 3;  // px-in-chunk 0..7
    const int m = l & 7;    // dest slot
#pragma unroll
    for (int i = 0; i < 9; i++) {
      const int idx = g + i * 4;        // 0..35, wave-uniform
      const int t = idx / 18;
      const int rr = (idx % 18) / 3, seg = idx % 3;
      const int iy = min(max(oy + rr, 0), HH - 1);
      const int tcol = seg * 8 + tc;
      const int ix = min(max(ox + tcol, 0), WW - 1);
      const int sc = (m - tcol) & 7;
      stage1k(srcs[t] + (((iy << 7) + ix) << 6) + sc * 8,
              &tile[((t * 6 + rr) * 24 + seg * 8) << 6]);
    }
  }

  f32x4 acc0 = {0.f, 0.f, 0.f, 0.f}, acc1 = {0.f, 0.f, 0.f, 0.f};
  const bf16x8* wp = (const bf16x8*)wtoff + l;

  __syncthreads();  // tile staged

#pragma unroll
  for (int k = 0; k < 9; k++) {
    const int ky = k / 3, kx = k - ky * 3;
    const int hh = h + ky - 1, ww2 = w + kx - 1;
    const bool valid = (hh >= 0) & (hh < HH) & (ww2 >= 0) & (ww2 < WW);
    const int tr = g + ky;      // 0..5
    const int tcx = col + kx;   // 0..17
#pragma unroll
    for (int cs = 0; cs < 4; cs++) {
      const int t = cs >> 1;
      const int chunk = (cs & 1) * 4 + quad;  // 0..7 within pixel
      bf16x8 v = *(const bf16x8*)&tile[(((t * 6 + tr) * 24 + tcx) << 6) +
                                       (((chunk + tcx) & 7) << 3)];
      if (!valid) v = (bf16x8)(short)0;
      const int f = (k * 4 + cs) * 2;
      acc0 = __builtin_amdgcn_mfma_f32_16x16x32_bf16(wp[f * 64], v, acc0, 0, 0, 0);
      acc1 = __builtin_amdgcn_mfma_f32_16x16x32_bf16(wp[(f + 1) * 64], v, acc1, 0, 0, 0);
    }
  }

  // planar output: out[o][pix], coalesced 64B stores
#pragma unroll
  for (int r = 0; r < 4; r++)
    out[(quad * 4 + r) * TOTPIX + pix] = acc0[r] + bias[quad * 4 + r];
  if (quad == 0) {
    out[16 * TOTPIX + pix] = acc1[0] + bias[16];
    out[17 * TOTPIX + pix] = acc1[1] + bias[17];
  }
}

// ---------- LDS-tiled MFMA deformable conv (r12 structure) ----------
// Block = 512 thr = 8 row-waves; output tile 8x16 px; halo 16x24 px
// (49KB, chunk-swizzled). Offsets read PLANAR (coalesced dword loads).
#define TH 16
#define TWP 24
__global__ __launch_bounds__(512, 4) void deform_tile_kernel(
    const short* __restrict__ x, const float* __restrict__ off,
    const short* __restrict__ wtd, const float* __restrict__ bias,
    float* __restrict__ outf, short* __restrict__ outb) {
  __shared__ short tile[TH * TWP * 64];  // 49152 B
  int bid = blockIdx.x;
  bid = (bid & 7) * (gridDim.x >> 3) + (bid >> 3);  // 512 % 8 == 0
  const int tid = threadIdx.x;
  const int l = tid & 63;
  const int wv = __builtin_amdgcn_readfirstlane(tid >> 6);  // 0..7
  const int col = l & 15, quad = l >> 4;
  const int b = bid >> 7;
  const int rem = bid & 127;
  const int h0 = (rem >> 3) * 8;   // 16 row-tiles
  const int w0 = (rem & 7) * 16;   // 8 col-tiles
  const int oy = h0 - 4, ox = w0 - 4;
  const int h = h0 + wv, w = w0 + col;
  const int pix = ((b << 7) + h) * WW + w;

  const short* xb = x + (size_t)b * (HW * 64);

  // ---- stage 16x24-px halo tile, chunk-swizzled source ----
  {
    const int tc = ((l >> 3) & 7);
    const int m = l & 7;
#pragma unroll
    for (int i = 0; i < 6; i++) {
      const int idx = wv + i * 8;        // 0..47
      const int r = idx / 3, seg = idx % 3;
      const int iy = min(max(oy + r, 0), HH - 1);
      const int tcol = seg * 8 + tc;
      const int ix = min(max(ox + tcol, 0), WW - 1);
      const int sc = (m - tcol) & 7;
      stage1k(xb + (((iy << 7) + ix) << 6) + sc * 8,
              &tile[((r * TWP + seg * 8) << 6)]);
    }
  }

  // planar offsets: off[j][pix], 18 coalesced dword loads
  float offv[18];
#pragma unroll
  for (int j = 0; j < 18; j++) offv[j] = off[j * TOTPIX + pix];

  f32x4 acc[4];
#pragma unroll
  for (int ot = 0; ot < 4; ot++)
#pragma unroll
    for (int r = 0; r < 4; r++) acc[ot][r] = 0.f;

  const int c0g = quad * 8;
  const bf16x8* wp = (const bf16x8*)wtd + l;

  __syncthreads();  // tile staged

#pragma unroll
  for (int k = 0; k < 9; k++) {
    const int ky = k / 3, kx = k - ky * 3;
    const float py = (float)(h - 1 + ky) + offv[2 * k];
    const float pxx = (float)(w - 1 + kx) + offv[2 * k + 1];
    const float y0f = floorf(py), x0f = floorf(pxx);
    const float ly = py - y0f, lx = pxx - x0f;
    const int y0 = (int)y0f, x0 = (int)x0f;
    const int y1 = y0 + 1, x1 = x0 + 1;
    float w00 = (1.f - ly) * (1.f - lx), w01 = (1.f - ly) * lx;
    float w10 = ly * (1.f - lx), w11 = ly * lx;
    if (y0 < 0 || y0 >= HH) { w00 = 0.f; w01 = 0.f; }
    if (y1 < 0 || y1 >= HH) { w10 = 0.f; w11 = 0.f; }
    if (x0 < 0 || x0 >= WW) { w00 = 0.f; w10 = 0.f; }
    if (x1 < 0 || x1 >= WW) { w01 = 0.f; w11 = 0.f; }
    const int cy0 = min(max(y0, 0), HH - 1), cy1 = min(max(y1, 0), HH - 1);
    const int cx0 = min(max(x0, 0), WW - 1), cx1 = min(max(x1, 0), WW - 1);

    const int ty0 = cy0 - oy, ty1 = cy1 - oy;
    const int tx0 = cx0 - ox, tx1 = cx1 - ox;
    const bool intile = (ty0 >= 0) & (ty1 < TH) & (tx0 >= 0) & (tx1 < TWP);

    bf16x8 v00a, v00b, v01a, v01b, v10a, v10b, v11a, v11b;
    if (__builtin_amdgcn_ballot_w64(intile) == ~0ull) {
      const int p00 = ((ty0 * TWP + tx0) << 6);
      const int p01 = ((ty0 * TWP + tx1) << 6);
      const int p10 = ((ty1 * TWP + tx0) << 6);
      const int p11 = ((ty1 * TWP + tx1) << 6);
      v00a = *(const bf16x8*)&tile[p00 + (((quad + tx0) & 7) << 3)];
      v00b = *(const bf16x8*)&tile[p00 + (((quad + 4 + tx0) & 7) << 3)];
      v01a = *(const bf16x8*)&tile[p01 + (((quad + tx1) & 7) << 3)];
      v01b = *(const bf16x8*)&tile[p01 + (((quad + 4 + tx1) & 7) << 3)];
      v10a = *(const bf16x8*)&tile[p10 + (((quad + tx0) & 7) << 3)];
      v10b = *(const bf16x8*)&tile[p10 + (((quad + 4 + tx0) & 7) << 3)];
      v11a = *(const bf16x8*)&tile[p11 + (((quad + tx1) & 7) << 3)];
      v11b = *(const bf16x8*)&tile[p11 + (((quad + 4 + tx1) & 7) << 3)];
    } else {
      const int p00 = ((cy0 * WW + cx0) << 6) + c0g;
      const int p01 = ((cy0 * WW + cx1) << 6) + c0g;
      const int p10 = ((cy1 * WW + cx0) << 6) + c0g;
      const int p11 = ((cy1 * WW + cx1) << 6) + c0g;
      v00a = *(const bf16x8*)(xb + p00);
      v00b = *(const bf16x8*)(xb + p00 + 32);
      v01a = *(const bf16x8*)(xb + p01);
      v01b = *(const bf16x8*)(xb + p01 + 32);
      v10a = *(const bf16x8*)(xb + p10);
      v10b = *(const bf16x8*)(xb + p10 + 32);
      v11a = *(const bf16x8*)(xb + p11);
      v11b = *(const bf16x8*)(xb + p11 + 32);
    }

    bf16x8 bs0, bs1;
#pragma unroll
    for (int j = 0; j < 8; j++) {
      float sa = bf2f(v00a[j]) * w00 + bf2f(v01a[j]) * w01 +
                 bf2f(v10a[j]) * w10 + bf2f(v11a[j]) * w11;
      bs0[j] = f2bf(sa);
      float sb = bf2f(v00b[j]) * w00 + bf2f(v01b[j]) * w01 +
                 bf2f(v10b[j]) * w10 + bf2f(v11b[j]) * w11;
      bs1[j] = f2bf(sb);
    }

    acc[0] = __builtin_amdgcn_mfma_f32_16x16x32_bf16(wp[(k * 8 + 0) * 64], bs0, acc[0], 0, 0, 0);
    acc[1] = __builtin_amdgcn_mfma_f32_16x16x32_bf16(wp[(k * 8 + 1) * 64], bs0, acc[1], 0, 0, 0);
    acc[2] = __builtin_amdgcn_mfma_f32_16x16x32_bf16(wp[(k * 8 + 2) * 64], bs0, acc[2], 0, 0, 0);
    acc[3] = __builtin_amdgcn_mfma_f32_16x16x32_bf16(wp[(k * 8 + 3) * 64], bs0, acc[3], 0, 0, 0);
    acc[0] = __builtin_amdgcn_mfma_f32_16x16x32_bf16(wp[(k * 8 + 4) * 64], bs1, acc[0], 0, 0, 0);
    acc[1] = __builtin_amdgcn_mfma_f32_16x16x32_bf16(wp[(k * 8 + 5) * 64], bs1, acc[1], 0, 0, 0);
    acc[2] = __builtin_amdgcn_mfma_f32_16x16x32_bf16(wp[(k * 8 + 6) * 64], bs1, acc[2], 0, 0, 0);
    acc[3] = __builtin_amdgcn_mfma_f32_16x16x32_bf16(wp[(k * 8 + 7) * 64], bs1, acc[3], 0, 0, 0);
  }

#pragma unroll
  for (int ot = 0; ot < 4; ot++)
#pragma unroll
    for (int r = 0; r < 4; r++)
      acc[ot][r] += bias[ot * 16 + quad * 4 + r];

  if (outb) {
#pragma unroll
    for (int ot = 0; ot < 4; ot++) {
      short4 sv;
      sv.x = f2bf(acc[ot][0]); sv.y = f2bf(acc[ot][1]);
      sv.z = f2bf(acc[ot][2]); sv.w = f2bf(acc[ot][3]);
      *(short4*)(outb + (size_t)pix * 64 + ot * 16 + quad * 4) = sv;
    }
  }
  if (outf) {
    const int hw = pix & (HW - 1);
#pragma unroll
    for (int ot = 0; ot < 4; ot++)
#pragma unroll
      for (int r = 0; r < 4; r++) {
        const int o = ot * 16 + quad * 4 + r;
        outf[(size_t)b * (CC * HW) + (size_t)o * HW + hw] = acc[ot][r];
      }
  }
}

extern "C" void kernel_launch(void* const* d_in, const int* in_sizes, int n_in,
                              void* d_out, int out_size, void* d_ws, size_t ws_size,
                              hipStream_t stream) {
  const float* ref    = (const float*)d_in[0];
  const float* nbr    = (const float*)d_in[1];
  const float* w_off1 = (const float*)d_in[2];
  const float* b_off1 = (const float*)d_in[3];
  const float* w_d1   = (const float*)d_in[4];
  const float* b_d1   = (const float*)d_in[5];
  const float* w_off2 = (const float*)d_in[6];
  const float* b_off2 = (const float*)d_in[7];
  const float* w_d2   = (const float*)d_in[8];
  const float* b_d2   = (const float*)d_in[9];
  const float* w_off3 = (const float*)d_in[10];
  const float* b_off3 = (const float*)d_in[11];
  const float* w_d3   = (const float*)d_in[12];
  const float* b_d3   = (const float*)d_in[13];

  float* out = (float*)d_out;
  char* ws = (char*)d_ws;
  float* off_buf = (float*)(ws);               // planar 18*65536*4 = 4,718,592 B
  short* ref_bf  = (short*)(ws + 5242880);     // 8,388,608 B each
  short* nbr_bf  = (short*)(ws + 13631488);
  short* d1_bf   = (short*)(ws + 22020096);
  short* d2_bf   = (short*)(ws + 30408704);
  short* wtd1    = (short*)(ws + 38797312);    // 73,728 B each
  short* wtd2    = (short*)(ws + 38871040);
  short* wtd3    = (short*)(ws + 38944768);
  short* wtoff1  = (short*)(ws + 39018496);
  short* wtoff2  = (short*)(ws + 39092224);
  short* wtoff3  = (short*)(ws + 39165952);

  cast_nhwc_kernel<<<1024, 256, 0, stream>>>(ref, nbr, ref_bf, nbr_bf);
  prep_weights_all<<<432, 256, 0, stream>>>(
      w_d1, w_off1, wtd1, wtoff1,
      w_d2, w_off2, wtd2, wtoff2,
      w_d3, w_off3, wtd3, wtoff3);

  const int nblk_oc = BB * HW / 64;   // 1024 tiles of 4x16 px
  const int nblk_df = BB * HW / 128;  // 512 tiles of 8x16 px

  off_tile_kernel<<<nblk_oc, 256, 0, stream>>>(ref_bf, nbr_bf, wtoff1, b_off1, off_buf);
  deform_tile_kernel<<<nblk_df, 512, 0, stream>>>(nbr_bf, off_buf, wtd1, b_d1, nullptr, d1_bf);
  off_tile_kernel<<<nblk_oc, 256, 0, stream>>>(ref_bf, d1_bf, wtoff2, b_off2, off_buf);
  deform_tile_kernel<<<nblk_df, 512, 0, stream>>>(d1_bf, off_buf, wtd2, b_d2, nullptr, d2_bf);
  off_tile_kernel<<<nblk_oc, 256, 0, stream>>>(ref_bf, d2_bf, wtoff3, b_off3, off_buf);
  deform_tile_kernel<<<nblk_df, 512, 0, stream>>>(d2_bf, off_buf, wtd3, b_d3, out, nullptr);
}